// Round 12
// baseline (320.851 us; speedup 1.0000x reference)
//
#include <hip/hip_runtime.h>
#include <math.h>

// Problem constants
#define DIMC 256   // input channels
#define NCH  176   // 128 q + 16 k + 32 v output channels
#define MM   1024  // N2 spatial
#define BB   16    // batch
#define KD   16    // DIM_K
#define HH   8     // heads
#define VD   32    // DIM_V
#define EPSV 1e-5
#define OPAD 192   // padded output channels for MFMA proj (12 o-tiles)

typedef short short8 __attribute__((ext_vector_type(8)));
typedef float f32x4  __attribute__((ext_vector_type(4)));
typedef unsigned u32x4v __attribute__((ext_vector_type(4)));

union frag8 { unsigned u[4]; short8 s; u32x4v v; };

__device__ __forceinline__ unsigned bf16rne(float f) {
    unsigned u = __float_as_uint(f);
    unsigned r = u + 0x7FFFu + ((u >> 16) & 1u);
    return r >> 16;
}
__device__ __forceinline__ float bf16tof(unsigned h) {
    return __uint_as_float(h << 16);
}

#define GL2LDS16(g, l) __builtin_amdgcn_global_load_lds( \
    (const __attribute__((address_space(1))) unsigned*)(g), \
    (__attribute__((address_space(3))) unsigned*)(l), 16, 0, 0)

// ---------------------------------------------------------------------------
// k_wprep (unchanged)
// ---------------------------------------------------------------------------
__global__ __launch_bounds__(256) void k_wprep(
    const float* __restrict__ wq_re, const float* __restrict__ wq_im,
    const float* __restrict__ wk_re, const float* __restrict__ wk_im,
    const float* __restrict__ wv_re, const float* __restrict__ wv_im,
    unsigned* __restrict__ Wpk)
{
    int idx = blockIdx.x * 256 + threadIdx.x;   // 0..24575
    if (idx >= OPAD * 128) return;
    int o = idx >> 7, j = idx & 127;
    int c0 = 2 * j;
    float r0 = 0.f, r1 = 0.f, i0 = 0.f, i1 = 0.f;
    if (o < 128) {
        r0 = wq_re[o * DIMC + c0]; r1 = wq_re[o * DIMC + c0 + 1];
        i0 = wq_im[o * DIMC + c0]; i1 = wq_im[o * DIMC + c0 + 1];
    } else if (o < 144) {
        int oo = o - 128;
        r0 = wk_re[oo * DIMC + c0]; r1 = wk_re[oo * DIMC + c0 + 1];
        i0 = wk_im[oo * DIMC + c0]; i1 = wk_im[oo * DIMC + c0 + 1];
    } else if (o < 176) {
        int oo = o - 144;
        r0 = wv_re[oo * DIMC + c0]; r1 = wv_re[oo * DIMC + c0 + 1];
        i0 = wv_im[oo * DIMC + c0]; i1 = wv_im[oo * DIMC + c0 + 1];
    }
    unsigned rh0 = bf16rne(r0), rh1 = bf16rne(r1);
    unsigned ih0 = bf16rne(i0), ih1 = bf16rne(i1);
    float rl0 = r0 - bf16tof(rh0), rl1 = r1 - bf16tof(rh1);
    float il0 = i0 - bf16tof(ih0), il1 = i1 - bf16tof(ih1);
    Wpk[0 * OPAD * 128 + idx] = rh0 | (rh1 << 16);
    Wpk[1 * OPAD * 128 + idx] = ih0 | (ih1 << 16);
    Wpk[2 * OPAD * 128 + idx] = bf16rne(rl0) | (bf16rne(rl1) << 16);
    Wpk[3 * OPAD * 128 + idx] = bf16rne(il0) | (bf16rne(il1) << 16);
}

// ---------------------------------------------------------------------------
// k_proj (swizzled Wsh, float4 X staging — unchanged from R10)
// ---------------------------------------------------------------------------
__global__ __launch_bounds__(256, 2) void k_proj(
    const float* __restrict__ x_re, const float* __restrict__ x_im,
    const unsigned* __restrict__ Wpk,
    float2* __restrict__ O)
{
    const int m0  = blockIdx.x * 32;
    const int b   = blockIdx.y;
    const int tid = threadIdx.x;
    const int w    = tid >> 6;
    const int lane = tid & 63;
    const int quad = lane >> 4;
    const int col  = lane & 15;
    const int mt = w & 1, og = w >> 1;

    __shared__ __align__(16) unsigned Wsh[4 * OPAD * 16];  // 48 KB
    __shared__ __align__(16) unsigned Xsh[4 * 32 * 20];    // 10 KB

    f32x4 accR[6], accI[6];
#pragma unroll
    for (int t = 0; t < 6; ++t) {
        accR[t] = (f32x4){0.f, 0.f, 0.f, 0.f};
        accI[t] = (f32x4){0.f, 0.f, 0.f, 0.f};
    }

    const int cl = tid >> 3;           // c within chunk, 0..31
    const int m4 = (tid & 7) * 4;      // m offset (x4)
    const int cp = cl >> 1, half = cl & 1;

#pragma unroll 1
    for (int kk = 0; kk < 8; ++kk) {
#pragma unroll
        for (int p = 0; p < 12; ++p) {
            int idx = p * 256 + tid;
            int plane = idx / 768;
            int rem = idx - plane * 768;
            int row = rem >> 2, seg = rem & 3;
            int sw = (row + (row >> 2)) & 3;
            u32x4v d = *(const u32x4v*)&Wpk[(size_t)plane * (OPAD * 128) + row * 128 + kk * 16 + seg * 4];
            *(u32x4v*)&Wsh[(plane * OPAD + row) * 16 + ((seg ^ sw) << 2)] = d;
        }
        {
            size_t base = ((size_t)(b * DIMC + kk * 32 + cl)) * MM + m0 + m4;
            float4 xr = *(const float4*)&x_re[base];
            float4 xi = *(const float4*)&x_im[base];
            unsigned short* xs = (unsigned short*)Xsh;
            const float* xrf = (const float*)&xr;
            const float* xif = (const float*)&xi;
#pragma unroll
            for (int j = 0; j < 4; ++j) {
                float r = xrf[j], iv = xif[j];
                unsigned rh = bf16rne(r), ih = bf16rne(iv);
                float rl = r - bf16tof(rh), il = iv - bf16tof(ih);
                int m = m4 + j;
                xs[(0 * 640 + m * 20 + cp) * 2 + half] = (unsigned short)rh;
                xs[(1 * 640 + m * 20 + cp) * 2 + half] = (unsigned short)ih;
                xs[(2 * 640 + m * 20 + cp) * 2 + half] = (unsigned short)bf16rne(rl);
                xs[(3 * 640 + m * 20 + cp) * 2 + half] = (unsigned short)bf16rne(il);
            }
        }
        __syncthreads();

        int mrow = mt * 16 + col;
        short8 Xrh = *(const short8*)&Xsh[0 * 640 + mrow * 20 + quad * 4];
        short8 Xih = *(const short8*)&Xsh[1 * 640 + mrow * 20 + quad * 4];
        short8 Xrl = *(const short8*)&Xsh[2 * 640 + mrow * 20 + quad * 4];
        short8 Xil = *(const short8*)&Xsh[3 * 640 + mrow * 20 + quad * 4];

#pragma unroll
        for (int ot = 0; ot < 6; ++ot) {
            int orow = (og * 6 + ot) * 16 + col;
            int swq = (quad ^ ((orow + (orow >> 2)) & 3)) << 2;
            frag8 Arh, Aih, Arl, Ail, Anh, Anl;
            Arh.s = *(const short8*)&Wsh[(0 * OPAD + orow) * 16 + swq];
            Aih.s = *(const short8*)&Wsh[(1 * OPAD + orow) * 16 + swq];
            Arl.s = *(const short8*)&Wsh[(2 * OPAD + orow) * 16 + swq];
            Ail.s = *(const short8*)&Wsh[(3 * OPAD + orow) * 16 + swq];
#pragma unroll
            for (int i = 0; i < 4; ++i) {
                Anh.u[i] = Aih.u[i] ^ 0x80008000u;
                Anl.u[i] = Ail.u[i] ^ 0x80008000u;
            }
            accR[ot] = __builtin_amdgcn_mfma_f32_16x16x32_bf16(Arh.s, Xrh, accR[ot], 0, 0, 0);
            accR[ot] = __builtin_amdgcn_mfma_f32_16x16x32_bf16(Anh.s, Xih, accR[ot], 0, 0, 0);
            accR[ot] = __builtin_amdgcn_mfma_f32_16x16x32_bf16(Arh.s, Xrl, accR[ot], 0, 0, 0);
            accR[ot] = __builtin_amdgcn_mfma_f32_16x16x32_bf16(Anh.s, Xil, accR[ot], 0, 0, 0);
            accR[ot] = __builtin_amdgcn_mfma_f32_16x16x32_bf16(Arl.s, Xrh, accR[ot], 0, 0, 0);
            accR[ot] = __builtin_amdgcn_mfma_f32_16x16x32_bf16(Anl.s, Xih, accR[ot], 0, 0, 0);
            accI[ot] = __builtin_amdgcn_mfma_f32_16x16x32_bf16(Arh.s, Xih, accI[ot], 0, 0, 0);
            accI[ot] = __builtin_amdgcn_mfma_f32_16x16x32_bf16(Aih.s, Xrh, accI[ot], 0, 0, 0);
            accI[ot] = __builtin_amdgcn_mfma_f32_16x16x32_bf16(Arh.s, Xil, accI[ot], 0, 0, 0);
            accI[ot] = __builtin_amdgcn_mfma_f32_16x16x32_bf16(Aih.s, Xrl, accI[ot], 0, 0, 0);
            accI[ot] = __builtin_amdgcn_mfma_f32_16x16x32_bf16(Arl.s, Xih, accI[ot], 0, 0, 0);
            accI[ot] = __builtin_amdgcn_mfma_f32_16x16x32_bf16(Ail.s, Xrh, accI[ot], 0, 0, 0);
        }
        __syncthreads();
    }

#pragma unroll
    for (int ot = 0; ot < 6; ++ot) {
        int gto = og * 6 + ot;
        if (gto >= 11) continue;
#pragma unroll
        for (int r = 0; r < 4; ++r) {
            int o = gto * 16 + quad * 4 + r;
            O[((size_t)(b * NCH + o)) * MM + m0 + mt * 16 + col] =
                make_float2(accR[ot][r], accI[ot][r]);
        }
    }
}

// ---------------------------------------------------------------------------
// K2: split-K BN stats (unchanged from R10)
// ---------------------------------------------------------------------------
__global__ __launch_bounds__(256) void k_bnstats_part(
    const float2* __restrict__ O, double* __restrict__ part)
{
    const int ch = blockIdx.x, q = blockIdx.y;
    const int o  = (ch < 128) ? ch : (144 + ch - 128);
    const int tid = threadIdx.x;

    double sr = 0, si = 0, sq = 0, sri = 0;
    for (int idx = tid; idx < 4 * MM; idx += 256) {
        int b = q * 4 + (idx >> 10), m = idx & 1023;
        float2 val = O[((size_t)(b * NCH + o)) * MM + m];
        double r = val.x, ii = val.y;
        sr += r; si += ii; sq += r * r - ii * ii; sri += r * ii;
    }
    __shared__ double red[4][256];
    red[0][tid] = sr; red[1][tid] = si; red[2][tid] = sq; red[3][tid] = sri;
    __syncthreads();
    for (int s = 128; s > 0; s >>= 1) {
        if (tid < s) {
            red[0][tid] += red[0][tid + s]; red[1][tid] += red[1][tid + s];
            red[2][tid] += red[2][tid + s]; red[3][tid] += red[3][tid + s];
        }
        __syncthreads();
    }
    if (tid == 0) {
        double* p = part + ((size_t)(ch * 4 + q)) * 4;
        p[0] = red[0][0]; p[1] = red[1][0]; p[2] = red[2][0]; p[3] = red[3][0];
    }
}

__global__ __launch_bounds__(64) void k_bnstats_fin(
    const double* __restrict__ part,
    const float* __restrict__ qs_re, const float* __restrict__ qs_im,
    const float* __restrict__ qb_re, const float* __restrict__ qb_im,
    const float* __restrict__ vs_re, const float* __restrict__ vs_im,
    const float* __restrict__ vb_re, const float* __restrict__ vb_im,
    float4* __restrict__ stats)
{
    int ch = blockIdx.x * 64 + threadIdx.x;
    if (ch >= 160) return;
    double sr = 0, si = 0, sq = 0, sri = 0;
#pragma unroll
    for (int q = 0; q < 4; ++q) {
        const double* p = part + ((size_t)(ch * 4 + q)) * 4;
        sr += p[0]; si += p[1]; sq += p[2]; sri += p[3];
    }
    const double inv = 1.0 / (double)(BB * MM);
    double mr = sr * inv, mi = si * inv;
    double vr = sq * inv - (mr * mr - mi * mi) + EPSV;
    double vi = 2.0 * (sri * inv - mr * mi);
    double rad = sqrt(vr * vr + vi * vi);
    double wr  = sqrt(fmax(0.5 * (rad + vr), 0.0));
    double wi  = sqrt(fmax(0.5 * (rad - vr), 0.0));
    if (vi < 0) wi = -wi;
    double den = wr * wr + wi * wi;
    double ivr = wr / den, ivi = -wi / den;
    double scr, sci, shr, shi;
    if (ch < 128) { scr = qs_re[ch]; sci = qs_im[ch]; shr = qb_re[ch]; shi = qb_im[ch]; }
    else { int i2 = ch - 128; scr = vs_re[i2]; sci = vs_im[i2]; shr = vb_re[i2]; shi = vb_im[i2]; }
    double Ar = scr * ivr - sci * ivi;
    double Ai = scr * ivi + sci * ivr;
    double Br = shr - (Ar * mr - Ai * mi);
    double Bi = shi - (Ar * mi + Ai * mr);
    stats[ch] = make_float4((float)Ar, (float)Ai, (float)Br, (float)Bi);
}

// ---------------------------------------------------------------------------
// K3a: apply BN affine in place; v channels emit bf16 planes chunk-major
// (unchanged from R10)
// ---------------------------------------------------------------------------
__global__ __launch_bounds__(256) void k_bnapply(
    const float4* __restrict__ stats, float2* __restrict__ O,
    unsigned* __restrict__ VR, unsigned* __restrict__ VI)
{
    int ch = blockIdx.x, b = blockIdx.y;
    int o  = (ch < 128) ? ch : (144 + ch - 128);
    float4 s = stats[ch];
    float2* row = O + ((size_t)(b * NCH + o)) * MM;
    int tid = threadIdx.x;
    for (int mm = tid; mm < 512; mm += 256) {
        float4 two = *(float4*)&row[2 * mm];
        float nr0 = s.x * two.x - s.y * two.y + s.z;
        float ni0 = s.x * two.y + s.y * two.x + s.w;
        float nr1 = s.x * two.z - s.y * two.w + s.z;
        float ni1 = s.x * two.w + s.y * two.z + s.w;
        *(float4*)&row[2 * mm] = make_float4(nr0, ni0, nr1, ni1);
        if (ch >= 128) {
            int bv = b * VD + (ch - 128);
            int cC = mm >> 4, off = mm & 15;
            size_t idx = ((size_t)cC * 512 + bv) * 16 + off;
            VR[idx] = bf16rne(nr0) | (bf16rne(nr1) << 16);
            VI[idx] = bf16rne(ni0) | (bf16rne(ni1) << 16);
        }
    }
}

// ---------------------------------------------------------------------------
// k_softlam (unchanged)
// ---------------------------------------------------------------------------
__global__ __launch_bounds__(256) void k_softlam(
    const float2* __restrict__ O, float2* __restrict__ lamc)
{
    int kc = blockIdx.x, b = blockIdx.y;
    const float2* row = O + ((size_t)(b * NCH + 128 + kc)) * MM;
    int tid = threadIdx.x;
    __shared__ float red[256];
    __shared__ float skl[1024];

    float mag[4]; float mx = -1e30f;
#pragma unroll
    for (int j = 0; j < 4; ++j) {
        float2 v = row[tid + j * 256];
        mag[j] = sqrtf(v.x * v.x + v.y * v.y);
        mx = fmaxf(mx, mag[j]);
    }
    red[tid] = mx; __syncthreads();
    for (int s = 128; s > 0; s >>= 1) { if (tid < s) red[tid] = fmaxf(red[tid], red[tid + s]); __syncthreads(); }
    mx = red[0]; __syncthreads();
    float e[4]; float sum = 0.f;
#pragma unroll
    for (int j = 0; j < 4; ++j) { e[j] = expf(mag[j] - mx); sum += e[j]; }
    red[tid] = sum; __syncthreads();
    for (int s = 128; s > 0; s >>= 1) { if (tid < s) red[tid] += red[tid + s]; __syncthreads(); }
    float inv = 1.f / red[0];
#pragma unroll
    for (int j = 0; j < 4; ++j) skl[tid + j * 256] = e[j] * inv;
    __syncthreads();

    int v = tid >> 3, s8 = tid & 7;
    const float2* vrow = O + ((size_t)(b * NCH + 144 + v)) * MM;
    float ar = 0.f, ai = 0.f;
    for (int i = 0; i < 128; ++i) {
        int m = s8 * 128 + i;
        float wgt = skl[m]; float2 vv = vrow[m];
        ar += wgt * vv.x; ai += wgt * vv.y;
    }
    __shared__ float2 part[32][8];
    part[v][s8] = make_float2(ar, ai);
    __syncthreads();
    if (tid < 32) {
        float2 t = part[tid][0];
#pragma unroll
        for (int j = 1; j < 8; ++j) { t.x += part[tid][j].x; t.y += part[tid][j].y; }
        lamc[((size_t)(b * KD + kc)) * VD + tid] = t;
    }
}

// ---------------------------------------------------------------------------
// k_eprepD — embD[win(8)][di(63)][k(16)][48 slots] u32, unit-XOR-swizzled
// by p(k).  (unchanged from R9)
// ---------------------------------------------------------------------------
__global__ __launch_bounds__(256) void k_eprepD(
    const float* __restrict__ er, const float* __restrict__ ei,
    unsigned* __restrict__ embD)
{
    int idx = blockIdx.x * 256 + threadIdx.x;     // 0 .. 8*63*768-1
    if (idx >= 8 * 63 * 768) return;
    int s   = idx % 48;
    int k   = (idx / 48) % 16;
    int di  = (idx / 768) % 63;
    int win = idx / (768 * 63);
    int u_s = s >> 2, o = s & 3;
    int p   = (((k >> 1) & 1) << 1) | ((k >> 2) & 1);
    int dj2 = ((u_s ^ p) << 2) | o;               // logical dj offset
    int dj  = 28 - win * 4 + dj2;
    unsigned val = 0;
    if (dj <= 62) {
        int e = (di * 63 + dj) * 16 + k;
        val = bf16rne(er[e]) | (bf16rne(ei[e]) << 16);
    }
    embD[idx] = val;
}

// ---------------------------------------------------------------------------
// k_main (R12): R9 structure (emb LDS dbuf + 1 barrier/chunk, B reg-direct)
// with the register footprint cut for 3 waves/SIMD.
//  - VGPR_Count reports ARCH regs only; R9's true footprint was 124 arch +
//    64 AGPR acc = 188 -> exactly 2 waves/SIMD. Occupancy (not staging
//    structure) is the invariant that pinned k_main at ~124 µs across
//    R7/R8/R9: co-phased waves stall together with nobody to fill in.
//  - Cut: B-frag register double-buffer removed (-16 arch regs; B loaded at
//    chunk top, latency hidden by the extra wave). __launch_bounds__(256,3)
//    caps the total at ~170. Spill watch: WRITE_SIZE must stay ~125 MB.
// ---------------------------------------------------------------------------
__global__ __launch_bounds__(256, 3) void k_main(
    const float2* __restrict__ O,
    const unsigned* __restrict__ embD,
    const unsigned* __restrict__ VbfR,
    const unsigned* __restrict__ VbfI,
    const float2* __restrict__ lamc,
    float* __restrict__ out, int cplx)
{
    const int tid  = threadIdx.x;
    const int w    = tid >> 6;
    const int lane = tid & 63;
    const int quad = lane >> 4;
    const int col  = lane & 15;

    const int n0  = blockIdx.x * 4;
    const int bvq = blockIdx.y;        // 0..3, 128 bv rows each
    const int b0  = bvq * 4;
    const int ni  = n0 >> 5;
    const int nj0 = n0 & 31;
    const int win = nj0 >> 2;

    __shared__ __align__(16) unsigned embS[2][768];   // 6 KB emb dbuf
    __shared__ __align__(16) float2 lamqs[4096];      // 32 KB lamt + qsh

    f32x4 accr[4][2], acci[4][2];
#pragma unroll
    for (int g = 0; g < 4; ++g)
#pragma unroll
        for (int t = 0; t < 2; ++t) {
            accr[g][t] = (f32x4){0.f, 0.f, 0.f, 0.f};
            acci[g][t] = (f32x4){0.f, 0.f, 0.f, 0.f};
        }

    // B-frag direct-load base (row = bvq*128 + w*32 + t*16 + col)
    const unsigned* vR = VbfR + ((size_t)(bvq * 128 + w * 32 + col)) * 16 + quad * 4;
    const unsigned* vI = VbfI + ((size_t)(bvq * 128 + w * 32 + col)) * 16 + quad * 4;

    const unsigned* eDw = embD + (size_t)win * (63 * 768);

    // A-window reader constants
    const int p  = (((col >> 1) & 1) << 1) | ((col >> 2) & 1);
    const int aBase = col * 48;
    const int a0 = aBase + (((2 * quad)     ^ p) << 2);
    const int a1 = aBase + (((2 * quad + 1) ^ p) << 2);
    const int a2 = aBase + (((2 * quad + 2) ^ p) << 2);

    // prefetch chunk 0 emb -> embS[0] (waves 0..2)
    if (w < 3)
        GL2LDS16(eDw + (size_t)(31 - ni) * 768 + w * 256 + lane * 4,
                 (unsigned*)embS[0] + w * 256);

#pragma unroll 1
    for (int c = 0; c < 32; ++c) {
        __syncthreads();   // embS[c&1] published

        // prefetch emb for chunk c+1 (clamped; last iter rewrites same data)
        const int cn = (c + 1 < 32) ? (c + 1) : 31;
        if (w < 3)
            GL2LDS16(eDw + (size_t)(cn - ni + 31) * 768 + w * 256 + lane * 4,
                     (unsigned*)embS[cn & 1] + w * 256);

        // B-fragments for this chunk (register-direct, no dbuf)
        const size_t boff = (size_t)c * 8192;
        frag8 Br0, Br1, Bi0, Bi1;
        Br0.v = *(const u32x4v*)(vR + boff);
        Br1.v = *(const u32x4v*)(vR + boff + 256);
        Bi0.v = *(const u32x4v*)(vI + boff);
        Bi1.v = *(const u32x4v*)(vI + boff + 256);

        const unsigned* es = (const unsigned*)embS[c & 1];
        u32x4v W0 = *(const u32x4v*)&es[a0];
        u32x4v W1 = *(const u32x4v*)&es[a1];
        u32x4v W2 = *(const u32x4v*)&es[a2];
        unsigned W[12] = { W0.x, W0.y, W0.z, W0.w,
                           W1.x, W1.y, W1.z, W1.w,
                           W2.x, W2.y, W2.z, W2.w };

#pragma unroll
        for (int g = 0; g < 4; ++g) {
            const int o = 3 - g;                       // compile-time
            union { unsigned u[4]; short8 s; } Rr, Ri, Rin;
            Rr.u[0] = __builtin_amdgcn_perm(W[o + 1], W[o + 0], 0x05040100u);
            Rr.u[1] = __builtin_amdgcn_perm(W[o + 3], W[o + 2], 0x05040100u);
            Rr.u[2] = __builtin_amdgcn_perm(W[o + 5], W[o + 4], 0x05040100u);
            Rr.u[3] = __builtin_amdgcn_perm(W[o + 7], W[o + 6], 0x05040100u);
            Ri.u[0] = __builtin_amdgcn_perm(W[o + 1], W[o + 0], 0x07060302u);
            Ri.u[1] = __builtin_amdgcn_perm(W[o + 3], W[o + 2], 0x07060302u);
            Ri.u[2] = __builtin_amdgcn_perm(W[o + 5], W[o + 4], 0x07060302u);
            Ri.u[3] = __builtin_amdgcn_perm(W[o + 7], W[o + 6], 0x07060302u);
            Rin.u[0] = Ri.u[0] ^ 0x80008000u;
            Rin.u[1] = Ri.u[1] ^ 0x80008000u;
            Rin.u[2] = Ri.u[2] ^ 0x80008000u;
            Rin.u[3] = Ri.u[3] ^ 0x80008000u;
            accr[g][0] = __builtin_amdgcn_mfma_f32_16x16x32_bf16(Rr.s,  Br0.s, accr[g][0], 0, 0, 0);
            accr[g][0] = __builtin_amdgcn_mfma_f32_16x16x32_bf16(Rin.s, Bi0.s, accr[g][0], 0, 0, 0);
            acci[g][0] = __builtin_amdgcn_mfma_f32_16x16x32_bf16(Rr.s,  Bi0.s, acci[g][0], 0, 0, 0);
            acci[g][0] = __builtin_amdgcn_mfma_f32_16x16x32_bf16(Ri.s,  Br0.s, acci[g][0], 0, 0, 0);
            accr[g][1] = __builtin_amdgcn_mfma_f32_16x16x32_bf16(Rr.s,  Br1.s, accr[g][1], 0, 0, 0);
            accr[g][1] = __builtin_amdgcn_mfma_f32_16x16x32_bf16(Rin.s, Bi1.s, accr[g][1], 0, 0, 0);
            acci[g][1] = __builtin_amdgcn_mfma_f32_16x16x32_bf16(Rr.s,  Bi1.s, acci[g][1], 0, 0, 0);
            acci[g][1] = __builtin_amdgcn_mfma_f32_16x16x32_bf16(Ri.s,  Br1.s, acci[g][1], 0, 0, 0);
        }
    }

    // ---- stage q tile into qsh (upper half of shared)
#pragma unroll
    for (int it = 0; it < 8; ++it) {
        int idx = it * 256 + tid;
        int g = idx & 3, ch = (idx >> 2) & 127, bl = idx >> 9;
        lamqs[2048 + idx] = O[((size_t)((b0 + bl) * NCH + ch)) * MM + n0 + g];
    }

    // ---- hoist lam_c (g-invariant)
    float2 lcv[2][4];
#pragma unroll
    for (int t = 0; t < 2; ++t) {
        int bvl = w * 32 + t * 16 + col;
        int bloc = b0 + (bvl >> 5), v = bvl & 31;
#pragma unroll
        for (int r = 0; r < 4; ++r)
            lcv[t][r] = lamc[((size_t)(bloc * KD + quad * 4 + r)) * VD + v];
    }

    // ---- epilogue (fully unrolled; g compile-time)
    float2* lamt = lamqs;                    // [16k][128bv]
    float2* qsh  = lamqs + 2048;
    const int col128 = tid & 127;
    const int hb = (tid >> 7) * 4;
    const int bl = col128 >> 5, vY = col128 & 31;
    const int bY = b0 + bl;
    float2* op2 = (float2*)out;
#pragma unroll
    for (int g = 0; g < 4; ++g) {
        __syncthreads();
#pragma unroll
        for (int t = 0; t < 2; ++t) {
            int bvl = w * 32 + t * 16 + col;
#pragma unroll
            for (int r = 0; r < 4; ++r) {
                int k = quad * 4 + r;
                lamt[k * 128 + bvl] = make_float2(accr[g][t][r] + lcv[t][r].x,
                                                  acci[g][t][r] + lcv[t][r].y);
            }
        }
        __syncthreads();
        float yr[4], yi[4];
#pragma unroll
        for (int h = 0; h < 4; ++h) { yr[h] = 0.f; yi[h] = 0.f; }
#pragma unroll
        for (int k = 0; k < 16; ++k) {
            float2 l = lamt[k * 128 + col128];
#pragma unroll
            for (int h = 0; h < 4; ++h) {
                float2 q = qsh[(bl * 128 + (hb + h) * 16 + k) * 4 + g];
                yr[h] += q.x * l.x - q.y * l.y;
                yi[h] += q.x * l.y + q.y * l.x;
            }
        }
        int n = n0 + g;
        if (cplx) {
#pragma unroll
            for (int h = 0; h < 4; ++h)
                op2[((size_t)(bY * 256 + (hb + h) * 32 + vY)) * MM + n] = make_float2(yr[h], yi[h]);
        } else {
#pragma unroll
            for (int h = 0; h < 4; ++h)
                out[((size_t)(bY * 256 + (hb + h) * 32 + vY)) * MM + n] = yr[h];
        }
    }
}

// ---------------------------------------------------------------------------
extern "C" void kernel_launch(void* const* d_in, const int* in_sizes, int n_in,
                              void* d_out, int out_size, void* d_ws, size_t ws_size,
                              hipStream_t stream)
{
    const float* x_re  = (const float*)d_in[0];
    const float* x_im  = (const float*)d_in[1];
    const float* wq_re = (const float*)d_in[2];
    const float* wq_im = (const float*)d_in[3];
    const float* wk_re = (const float*)d_in[4];
    const float* wk_im = (const float*)d_in[5];
    const float* wv_re = (const float*)d_in[6];
    const float* wv_im = (const float*)d_in[7];
    const float* qs_re = (const float*)d_in[8];
    const float* qs_im = (const float*)d_in[9];
    const float* qb_re = (const float*)d_in[10];
    const float* qb_im = (const float*)d_in[11];
    const float* vs_re = (const float*)d_in[12];
    const float* vs_im = (const float*)d_in[13];
    const float* vb_re = (const float*)d_in[14];
    const float* vb_im = (const float*)d_in[15];
    const float* emb_re = (const float*)d_in[16];
    const float* emb_im = (const float*)d_in[17];

    float* ws = (float*)d_ws;
    const size_t O_OFF  = 0;                                     // 5,767,168
    const size_t ST_OFF = O_OFF + (size_t)BB * NCH * MM * 2;     // 640
    const size_t LC_OFF = ST_OFF + 640;                          // 16,384
    const size_t WP_OFF = LC_OFF + 16384;                        // 98,304 (Wpk)
    const size_t VR_OFF = WP_OFF + 98304;                        // 262,144
    const size_t VI_OFF = VR_OFF + 262144;                       // 262,144
    const size_t ED_OFF = VI_OFF + 262144;                       // 387,072 (embD)
    const size_t PT_OFF = ED_OFF + 387072;                       // partials

    float2*   O     = (float2*)(ws + O_OFF);
    float4*   stats = (float4*)(ws + ST_OFF);
    float2*   lamc  = (float2*)(ws + LC_OFF);
    unsigned* Wpk   = (unsigned*)(ws + WP_OFF);
    unsigned* VbfR  = (unsigned*)(ws + VR_OFF);
    unsigned* VbfI  = (unsigned*)(ws + VI_OFF);
    unsigned* embD  = (unsigned*)(ws + ED_OFF);
    double*   part  = (double*)(ws + PT_OFF);
    float*    outp  = (float*)d_out;

    int cplx = (out_size >= 2 * BB * 256 * MM) ? 1 : 0;

    k_wprep<<<dim3(96), 256, 0, stream>>>(wq_re, wq_im, wk_re, wk_im,
                                          wv_re, wv_im, Wpk);
    k_eprepD<<<dim3(1512), 256, 0, stream>>>(emb_re, emb_im, embD);
    k_proj<<<dim3(32, BB), 256, 0, stream>>>(x_re, x_im, Wpk, O);
    k_bnstats_part<<<dim3(160, 4), 256, 0, stream>>>(O, part);
    k_bnstats_fin<<<dim3(3), 64, 0, stream>>>(part, qs_re, qs_im, qb_re, qb_im,
                                              vs_re, vs_im, vb_re, vb_im, stats);
    k_bnapply<<<dim3(160, BB), 256, 0, stream>>>(stats, O, VbfR, VbfI);
    k_softlam<<<dim3(KD, BB), 256, 0, stream>>>(O, lamc);
    k_main<<<dim3(256, 4), 256, 0, stream>>>(O, embD, VbfR, VbfI, lamc, outp, cplx);
}

// Round 13
// 261.019 us; speedup vs baseline: 1.2292x; 1.2292x over previous
//
#include <hip/hip_runtime.h>
#include <math.h>

// Problem constants
#define DIMC 256   // input channels
#define NCH  176   // 128 q + 16 k + 32 v output channels
#define MM   1024  // N2 spatial
#define BB   16    // batch
#define KD   16    // DIM_K
#define HH   8     // heads
#define VD   32    // DIM_V
#define EPSV 1e-5
#define OPAD 192   // padded output channels for MFMA proj (12 o-tiles)

typedef short short8 __attribute__((ext_vector_type(8)));
typedef float f32x4  __attribute__((ext_vector_type(4)));
typedef unsigned u32x4v __attribute__((ext_vector_type(4)));

union frag8 { unsigned u[4]; short8 s; u32x4v v; };

__device__ __forceinline__ unsigned bf16rne(float f) {
    unsigned u = __float_as_uint(f);
    unsigned r = u + 0x7FFFu + ((u >> 16) & 1u);
    return r >> 16;
}
__device__ __forceinline__ float bf16tof(unsigned h) {
    return __uint_as_float(h << 16);
}

#define GL2LDS16(g, l) __builtin_amdgcn_global_load_lds( \
    (const __attribute__((address_space(1))) unsigned*)(g), \
    (__attribute__((address_space(3))) unsigned*)(l), 16, 0, 0)

// ---------------------------------------------------------------------------
// k_wprep (unchanged)
// ---------------------------------------------------------------------------
__global__ __launch_bounds__(256) void k_wprep(
    const float* __restrict__ wq_re, const float* __restrict__ wq_im,
    const float* __restrict__ wk_re, const float* __restrict__ wk_im,
    const float* __restrict__ wv_re, const float* __restrict__ wv_im,
    unsigned* __restrict__ Wpk)
{
    int idx = blockIdx.x * 256 + threadIdx.x;   // 0..24575
    if (idx >= OPAD * 128) return;
    int o = idx >> 7, j = idx & 127;
    int c0 = 2 * j;
    float r0 = 0.f, r1 = 0.f, i0 = 0.f, i1 = 0.f;
    if (o < 128) {
        r0 = wq_re[o * DIMC + c0]; r1 = wq_re[o * DIMC + c0 + 1];
        i0 = wq_im[o * DIMC + c0]; i1 = wq_im[o * DIMC + c0 + 1];
    } else if (o < 144) {
        int oo = o - 128;
        r0 = wk_re[oo * DIMC + c0]; r1 = wk_re[oo * DIMC + c0 + 1];
        i0 = wk_im[oo * DIMC + c0]; i1 = wk_im[oo * DIMC + c0 + 1];
    } else if (o < 176) {
        int oo = o - 144;
        r0 = wv_re[oo * DIMC + c0]; r1 = wv_re[oo * DIMC + c0 + 1];
        i0 = wv_im[oo * DIMC + c0]; i1 = wv_im[oo * DIMC + c0 + 1];
    }
    unsigned rh0 = bf16rne(r0), rh1 = bf16rne(r1);
    unsigned ih0 = bf16rne(i0), ih1 = bf16rne(i1);
    float rl0 = r0 - bf16tof(rh0), rl1 = r1 - bf16tof(rh1);
    float il0 = i0 - bf16tof(ih0), il1 = i1 - bf16tof(ih1);
    Wpk[0 * OPAD * 128 + idx] = rh0 | (rh1 << 16);
    Wpk[1 * OPAD * 128 + idx] = ih0 | (ih1 << 16);
    Wpk[2 * OPAD * 128 + idx] = bf16rne(rl0) | (bf16rne(rl1) << 16);
    Wpk[3 * OPAD * 128 + idx] = bf16rne(il0) | (bf16rne(il1) << 16);
}

// ---------------------------------------------------------------------------
// k_proj (swizzled Wsh, float4 X staging — unchanged)
// ---------------------------------------------------------------------------
__global__ __launch_bounds__(256, 2) void k_proj(
    const float* __restrict__ x_re, const float* __restrict__ x_im,
    const unsigned* __restrict__ Wpk,
    float2* __restrict__ O)
{
    const int m0  = blockIdx.x * 32;
    const int b   = blockIdx.y;
    const int tid = threadIdx.x;
    const int w    = tid >> 6;
    const int lane = tid & 63;
    const int quad = lane >> 4;
    const int col  = lane & 15;
    const int mt = w & 1, og = w >> 1;

    __shared__ __align__(16) unsigned Wsh[4 * OPAD * 16];  // 48 KB
    __shared__ __align__(16) unsigned Xsh[4 * 32 * 20];    // 10 KB

    f32x4 accR[6], accI[6];
#pragma unroll
    for (int t = 0; t < 6; ++t) {
        accR[t] = (f32x4){0.f, 0.f, 0.f, 0.f};
        accI[t] = (f32x4){0.f, 0.f, 0.f, 0.f};
    }

    const int cl = tid >> 3;
    const int m4 = (tid & 7) * 4;
    const int cp = cl >> 1, half = cl & 1;

#pragma unroll 1
    for (int kk = 0; kk < 8; ++kk) {
#pragma unroll
        for (int p = 0; p < 12; ++p) {
            int idx = p * 256 + tid;
            int plane = idx / 768;
            int rem = idx - plane * 768;
            int row = rem >> 2, seg = rem & 3;
            int sw = (row + (row >> 2)) & 3;
            u32x4v d = *(const u32x4v*)&Wpk[(size_t)plane * (OPAD * 128) + row * 128 + kk * 16 + seg * 4];
            *(u32x4v*)&Wsh[(plane * OPAD + row) * 16 + ((seg ^ sw) << 2)] = d;
        }
        {
            size_t base = ((size_t)(b * DIMC + kk * 32 + cl)) * MM + m0 + m4;
            float4 xr = *(const float4*)&x_re[base];
            float4 xi = *(const float4*)&x_im[base];
            unsigned short* xs = (unsigned short*)Xsh;
            const float* xrf = (const float*)&xr;
            const float* xif = (const float*)&xi;
#pragma unroll
            for (int j = 0; j < 4; ++j) {
                float r = xrf[j], iv = xif[j];
                unsigned rh = bf16rne(r), ih = bf16rne(iv);
                float rl = r - bf16tof(rh), il = iv - bf16tof(ih);
                int m = m4 + j;
                xs[(0 * 640 + m * 20 + cp) * 2 + half] = (unsigned short)rh;
                xs[(1 * 640 + m * 20 + cp) * 2 + half] = (unsigned short)ih;
                xs[(2 * 640 + m * 20 + cp) * 2 + half] = (unsigned short)bf16rne(rl);
                xs[(3 * 640 + m * 20 + cp) * 2 + half] = (unsigned short)bf16rne(il);
            }
        }
        __syncthreads();

        int mrow = mt * 16 + col;
        short8 Xrh = *(const short8*)&Xsh[0 * 640 + mrow * 20 + quad * 4];
        short8 Xih = *(const short8*)&Xsh[1 * 640 + mrow * 20 + quad * 4];
        short8 Xrl = *(const short8*)&Xsh[2 * 640 + mrow * 20 + quad * 4];
        short8 Xil = *(const short8*)&Xsh[3 * 640 + mrow * 20 + quad * 4];

#pragma unroll
        for (int ot = 0; ot < 6; ++ot) {
            int orow = (og * 6 + ot) * 16 + col;
            int swq = (quad ^ ((orow + (orow >> 2)) & 3)) << 2;
            frag8 Arh, Aih, Arl, Ail, Anh, Anl;
            Arh.s = *(const short8*)&Wsh[(0 * OPAD + orow) * 16 + swq];
            Aih.s = *(const short8*)&Wsh[(1 * OPAD + orow) * 16 + swq];
            Arl.s = *(const short8*)&Wsh[(2 * OPAD + orow) * 16 + swq];
            Ail.s = *(const short8*)&Wsh[(3 * OPAD + orow) * 16 + swq];
#pragma unroll
            for (int i = 0; i < 4; ++i) {
                Anh.u[i] = Aih.u[i] ^ 0x80008000u;
                Anl.u[i] = Ail.u[i] ^ 0x80008000u;
            }
            accR[ot] = __builtin_amdgcn_mfma_f32_16x16x32_bf16(Arh.s, Xrh, accR[ot], 0, 0, 0);
            accR[ot] = __builtin_amdgcn_mfma_f32_16x16x32_bf16(Anh.s, Xih, accR[ot], 0, 0, 0);
            accR[ot] = __builtin_amdgcn_mfma_f32_16x16x32_bf16(Arh.s, Xrl, accR[ot], 0, 0, 0);
            accR[ot] = __builtin_amdgcn_mfma_f32_16x16x32_bf16(Anh.s, Xil, accR[ot], 0, 0, 0);
            accR[ot] = __builtin_amdgcn_mfma_f32_16x16x32_bf16(Arl.s, Xrh, accR[ot], 0, 0, 0);
            accR[ot] = __builtin_amdgcn_mfma_f32_16x16x32_bf16(Anl.s, Xih, accR[ot], 0, 0, 0);
            accI[ot] = __builtin_amdgcn_mfma_f32_16x16x32_bf16(Arh.s, Xih, accI[ot], 0, 0, 0);
            accI[ot] = __builtin_amdgcn_mfma_f32_16x16x32_bf16(Aih.s, Xrh, accI[ot], 0, 0, 0);
            accI[ot] = __builtin_amdgcn_mfma_f32_16x16x32_bf16(Arh.s, Xil, accI[ot], 0, 0, 0);
            accI[ot] = __builtin_amdgcn_mfma_f32_16x16x32_bf16(Aih.s, Xrl, accI[ot], 0, 0, 0);
            accI[ot] = __builtin_amdgcn_mfma_f32_16x16x32_bf16(Arl.s, Xih, accI[ot], 0, 0, 0);
            accI[ot] = __builtin_amdgcn_mfma_f32_16x16x32_bf16(Ail.s, Xrh, accI[ot], 0, 0, 0);
        }
        __syncthreads();
    }

#pragma unroll
    for (int ot = 0; ot < 6; ++ot) {
        int gto = og * 6 + ot;
        if (gto >= 11) continue;
#pragma unroll
        for (int r = 0; r < 4; ++r) {
            int o = gto * 16 + quad * 4 + r;
            O[((size_t)(b * NCH + o)) * MM + m0 + mt * 16 + col] =
                make_float2(accR[ot][r], accI[ot][r]);
        }
    }
}

// ---------------------------------------------------------------------------
// K2: split-K BN stats (unchanged)
// ---------------------------------------------------------------------------
__global__ __launch_bounds__(256) void k_bnstats_part(
    const float2* __restrict__ O, double* __restrict__ part)
{
    const int ch = blockIdx.x, q = blockIdx.y;
    const int o  = (ch < 128) ? ch : (144 + ch - 128);
    const int tid = threadIdx.x;

    double sr = 0, si = 0, sq = 0, sri = 0;
    for (int idx = tid; idx < 4 * MM; idx += 256) {
        int b = q * 4 + (idx >> 10), m = idx & 1023;
        float2 val = O[((size_t)(b * NCH + o)) * MM + m];
        double r = val.x, ii = val.y;
        sr += r; si += ii; sq += r * r - ii * ii; sri += r * ii;
    }
    __shared__ double red[4][256];
    red[0][tid] = sr; red[1][tid] = si; red[2][tid] = sq; red[3][tid] = sri;
    __syncthreads();
    for (int s = 128; s > 0; s >>= 1) {
        if (tid < s) {
            red[0][tid] += red[0][tid + s]; red[1][tid] += red[1][tid + s];
            red[2][tid] += red[2][tid + s]; red[3][tid] += red[3][tid + s];
        }
        __syncthreads();
    }
    if (tid == 0) {
        double* p = part + ((size_t)(ch * 4 + q)) * 4;
        p[0] = red[0][0]; p[1] = red[1][0]; p[2] = red[2][0]; p[3] = red[3][0];
    }
}

__global__ __launch_bounds__(64) void k_bnstats_fin(
    const double* __restrict__ part,
    const float* __restrict__ qs_re, const float* __restrict__ qs_im,
    const float* __restrict__ qb_re, const float* __restrict__ qb_im,
    const float* __restrict__ vs_re, const float* __restrict__ vs_im,
    const float* __restrict__ vb_re, const float* __restrict__ vb_im,
    float4* __restrict__ stats)
{
    int ch = blockIdx.x * 64 + threadIdx.x;
    if (ch >= 160) return;
    double sr = 0, si = 0, sq = 0, sri = 0;
#pragma unroll
    for (int q = 0; q < 4; ++q) {
        const double* p = part + ((size_t)(ch * 4 + q)) * 4;
        sr += p[0]; si += p[1]; sq += p[2]; sri += p[3];
    }
    const double inv = 1.0 / (double)(BB * MM);
    double mr = sr * inv, mi = si * inv;
    double vr = sq * inv - (mr * mr - mi * mi) + EPSV;
    double vi = 2.0 * (sri * inv - mr * mi);
    double rad = sqrt(vr * vr + vi * vi);
    double wr  = sqrt(fmax(0.5 * (rad + vr), 0.0));
    double wi  = sqrt(fmax(0.5 * (rad - vr), 0.0));
    if (vi < 0) wi = -wi;
    double den = wr * wr + wi * wi;
    double ivr = wr / den, ivi = -wi / den;
    double scr, sci, shr, shi;
    if (ch < 128) { scr = qs_re[ch]; sci = qs_im[ch]; shr = qb_re[ch]; shi = qb_im[ch]; }
    else { int i2 = ch - 128; scr = vs_re[i2]; sci = vs_im[i2]; shr = vb_re[i2]; shi = vb_im[i2]; }
    double Ar = scr * ivr - sci * ivi;
    double Ai = scr * ivi + sci * ivr;
    double Br = shr - (Ar * mr - Ai * mi);
    double Bi = shi - (Ar * mi + Ai * mr);
    stats[ch] = make_float4((float)Ar, (float)Ai, (float)Br, (float)Bi);
}

// ---------------------------------------------------------------------------
// K3a: apply BN affine in place; v channels emit bf16 planes chunk-major
// (unchanged)
// ---------------------------------------------------------------------------
__global__ __launch_bounds__(256) void k_bnapply(
    const float4* __restrict__ stats, float2* __restrict__ O,
    unsigned* __restrict__ VR, unsigned* __restrict__ VI)
{
    int ch = blockIdx.x, b = blockIdx.y;
    int o  = (ch < 128) ? ch : (144 + ch - 128);
    float4 s = stats[ch];
    float2* row = O + ((size_t)(b * NCH + o)) * MM;
    int tid = threadIdx.x;
    for (int mm = tid; mm < 512; mm += 256) {
        float4 two = *(float4*)&row[2 * mm];
        float nr0 = s.x * two.x - s.y * two.y + s.z;
        float ni0 = s.x * two.y + s.y * two.x + s.w;
        float nr1 = s.x * two.z - s.y * two.w + s.z;
        float ni1 = s.x * two.w + s.y * two.z + s.w;
        *(float4*)&row[2 * mm] = make_float4(nr0, ni0, nr1, ni1);
        if (ch >= 128) {
            int bv = b * VD + (ch - 128);
            int cC = mm >> 4, off = mm & 15;
            size_t idx = ((size_t)cC * 512 + bv) * 16 + off;
            VR[idx] = bf16rne(nr0) | (bf16rne(nr1) << 16);
            VI[idx] = bf16rne(ni0) | (bf16rne(ni1) << 16);
        }
    }
}

// ---------------------------------------------------------------------------
// k_softlam (unchanged)
// ---------------------------------------------------------------------------
__global__ __launch_bounds__(256) void k_softlam(
    const float2* __restrict__ O, float2* __restrict__ lamc)
{
    int kc = blockIdx.x, b = blockIdx.y;
    const float2* row = O + ((size_t)(b * NCH + 128 + kc)) * MM;
    int tid = threadIdx.x;
    __shared__ float red[256];
    __shared__ float skl[1024];

    float mag[4]; float mx = -1e30f;
#pragma unroll
    for (int j = 0; j < 4; ++j) {
        float2 v = row[tid + j * 256];
        mag[j] = sqrtf(v.x * v.x + v.y * v.y);
        mx = fmaxf(mx, mag[j]);
    }
    red[tid] = mx; __syncthreads();
    for (int s = 128; s > 0; s >>= 1) { if (tid < s) red[tid] = fmaxf(red[tid], red[tid + s]); __syncthreads(); }
    mx = red[0]; __syncthreads();
    float e[4]; float sum = 0.f;
#pragma unroll
    for (int j = 0; j < 4; ++j) { e[j] = expf(mag[j] - mx); sum += e[j]; }
    red[tid] = sum; __syncthreads();
    for (int s = 128; s > 0; s >>= 1) { if (tid < s) red[tid] += red[tid + s]; __syncthreads(); }
    float inv = 1.f / red[0];
#pragma unroll
    for (int j = 0; j < 4; ++j) skl[tid + j * 256] = e[j] * inv;
    __syncthreads();

    int v = tid >> 3, s8 = tid & 7;
    const float2* vrow = O + ((size_t)(b * NCH + 144 + v)) * MM;
    float ar = 0.f, ai = 0.f;
    for (int i = 0; i < 128; ++i) {
        int m = s8 * 128 + i;
        float wgt = skl[m]; float2 vv = vrow[m];
        ar += wgt * vv.x; ai += wgt * vv.y;
    }
    __shared__ float2 part[32][8];
    part[v][s8] = make_float2(ar, ai);
    __syncthreads();
    if (tid < 32) {
        float2 t = part[tid][0];
#pragma unroll
        for (int j = 1; j < 8; ++j) { t.x += part[tid][j].x; t.y += part[tid][j].y; }
        lamc[((size_t)(b * KD + kc)) * VD + tid] = t;
    }
}

// ---------------------------------------------------------------------------
// k_eprepD (unchanged)
// ---------------------------------------------------------------------------
__global__ __launch_bounds__(256) void k_eprepD(
    const float* __restrict__ er, const float* __restrict__ ei,
    unsigned* __restrict__ embD)
{
    int idx = blockIdx.x * 256 + threadIdx.x;     // 0 .. 8*63*768-1
    if (idx >= 8 * 63 * 768) return;
    int s   = idx % 48;
    int k   = (idx / 48) % 16;
    int di  = (idx / 768) % 63;
    int win = idx / (768 * 63);
    int u_s = s >> 2, o = s & 3;
    int p   = (((k >> 1) & 1) << 1) | ((k >> 2) & 1);
    int dj2 = ((u_s ^ p) << 2) | o;               // logical dj offset
    int dj  = 28 - win * 4 + dj2;
    unsigned val = 0;
    if (dj <= 62) {
        int e = (di * 63 + dj) * 16 + k;
        val = bf16rne(er[e]) | (bf16rne(ei[e]) << 16);
    }
    embD[idx] = val;
}

// ---------------------------------------------------------------------------
// k_main (R13): shrink the ACCUMULATOR to fit 3 waves/SIMD honestly.
//  R12 proved the mechanism: (256,3) with a 64-AGPR acc forces arch VGPR=84
//  and spills (WRITE 290 MB). Fix: halve the bv tile (t: 2 -> 1; 64 bv rows
//  per block, grid.y 4 -> 8). acc 64 -> 32 AGPR, B-frags 32 -> 16 regs.
//  Budget: ~110 arch + 32 acc = ~142 <= 170 -> 3 waves/SIMD WITHOUT spill.
//  Cost: A L2 traffic doubles (+~7 µs device-wide) — paid for by the extra
//  wave filling memory-latency holes (m114 co-scheduling).
// ---------------------------------------------------------------------------
__global__ __launch_bounds__(256, 3) void k_main(
    const float2* __restrict__ O,
    const unsigned* __restrict__ embD,
    const unsigned* __restrict__ VbfR,
    const unsigned* __restrict__ VbfI,
    const float2* __restrict__ lamc,
    float* __restrict__ out, int cplx)
{
    const int tid  = threadIdx.x;
    const int w    = tid >> 6;
    const int lane = tid & 63;
    const int quad = lane >> 4;
    const int col  = lane & 15;

    const int n0  = blockIdx.x * 4;
    const int bvq = blockIdx.y;        // 0..7, 64 bv rows each
    const int b0  = bvq * 2;
    const int ni  = n0 >> 5;
    const int nj0 = n0 & 31;
    const int win = nj0 >> 2;

    __shared__ __align__(16) unsigned embS[2][768];   // 6 KB emb dbuf
    __shared__ __align__(16) float2 lamqs[2048];      // 8 KB lamt + 8 KB qsh

    f32x4 accr[4], acci[4];
#pragma unroll
    for (int g = 0; g < 4; ++g) {
        accr[g] = (f32x4){0.f, 0.f, 0.f, 0.f};
        acci[g] = (f32x4){0.f, 0.f, 0.f, 0.f};
    }

    // B-frag direct-load base (row = bvq*64 + w*16 + col)
    const unsigned* vR = VbfR + ((size_t)(bvq * 64 + w * 16 + col)) * 16 + quad * 4;
    const unsigned* vI = VbfI + ((size_t)(bvq * 64 + w * 16 + col)) * 16 + quad * 4;

    const unsigned* eDw = embD + (size_t)win * (63 * 768);

    // A-window reader constants
    const int p  = (((col >> 1) & 1) << 1) | ((col >> 2) & 1);
    const int aBase = col * 48;
    const int a0 = aBase + (((2 * quad)     ^ p) << 2);
    const int a1 = aBase + (((2 * quad + 1) ^ p) << 2);
    const int a2 = aBase + (((2 * quad + 2) ^ p) << 2);

    // prefetch chunk 0 emb -> embS[0] (waves 0..2)
    if (w < 3)
        GL2LDS16(eDw + (size_t)(31 - ni) * 768 + w * 256 + lane * 4,
                 (unsigned*)embS[0] + w * 256);

#pragma unroll 1
    for (int c = 0; c < 32; ++c) {
        __syncthreads();   // embS[c&1] published

        const int cn = (c + 1 < 32) ? (c + 1) : 31;
        if (w < 3)
            GL2LDS16(eDw + (size_t)(cn - ni + 31) * 768 + w * 256 + lane * 4,
                     (unsigned*)embS[cn & 1] + w * 256);

        // B-fragments for this chunk (register-direct, single tile)
        const size_t boff = (size_t)c * 8192;
        frag8 Br0, Bi0;
        Br0.v = *(const u32x4v*)(vR + boff);
        Bi0.v = *(const u32x4v*)(vI + boff);

        const unsigned* es = (const unsigned*)embS[c & 1];
        u32x4v W0 = *(const u32x4v*)&es[a0];
        u32x4v W1 = *(const u32x4v*)&es[a1];
        u32x4v W2 = *(const u32x4v*)&es[a2];
        unsigned W[12] = { W0.x, W0.y, W0.z, W0.w,
                           W1.x, W1.y, W1.z, W1.w,
                           W2.x, W2.y, W2.z, W2.w };

#pragma unroll
        for (int g = 0; g < 4; ++g) {
            const int o = 3 - g;                       // compile-time
            union { unsigned u[4]; short8 s; } Rr, Ri, Rin;
            Rr.u[0] = __builtin_amdgcn_perm(W[o + 1], W[o + 0], 0x05040100u);
            Rr.u[1] = __builtin_amdgcn_perm(W[o + 3], W[o + 2], 0x05040100u);
            Rr.u[2] = __builtin_amdgcn_perm(W[o + 5], W[o + 4], 0x05040100u);
            Rr.u[3] = __builtin_amdgcn_perm(W[o + 7], W[o + 6], 0x05040100u);
            Ri.u[0] = __builtin_amdgcn_perm(W[o + 1], W[o + 0], 0x07060302u);
            Ri.u[1] = __builtin_amdgcn_perm(W[o + 3], W[o + 2], 0x07060302u);
            Ri.u[2] = __builtin_amdgcn_perm(W[o + 5], W[o + 4], 0x07060302u);
            Ri.u[3] = __builtin_amdgcn_perm(W[o + 7], W[o + 6], 0x07060302u);
            Rin.u[0] = Ri.u[0] ^ 0x80008000u;
            Rin.u[1] = Ri.u[1] ^ 0x80008000u;
            Rin.u[2] = Ri.u[2] ^ 0x80008000u;
            Rin.u[3] = Ri.u[3] ^ 0x80008000u;
            accr[g] = __builtin_amdgcn_mfma_f32_16x16x32_bf16(Rr.s,  Br0.s, accr[g], 0, 0, 0);
            accr[g] = __builtin_amdgcn_mfma_f32_16x16x32_bf16(Rin.s, Bi0.s, accr[g], 0, 0, 0);
            acci[g] = __builtin_amdgcn_mfma_f32_16x16x32_bf16(Rr.s,  Bi0.s, acci[g], 0, 0, 0);
            acci[g] = __builtin_amdgcn_mfma_f32_16x16x32_bf16(Ri.s,  Br0.s, acci[g], 0, 0, 0);
        }
    }

    // ---- stage q tile into qsh (upper half of shared): [bl(2)][ch128][g4]
#pragma unroll
    for (int it = 0; it < 4; ++it) {
        int idx = it * 256 + tid;
        int g = idx & 3, ch = (idx >> 2) & 127, bl = idx >> 9;
        lamqs[1024 + idx] = O[((size_t)((b0 + bl) * NCH + ch)) * MM + n0 + g];
    }

    // ---- hoist lam_c (g-invariant)
    float2 lcv[4];
    {
        int bvl = w * 16 + col;
        int bloc = b0 + (bvl >> 5), v = bvl & 31;
#pragma unroll
        for (int r = 0; r < 4; ++r)
            lcv[r] = lamc[((size_t)(bloc * KD + quad * 4 + r)) * VD + v];
    }

    // ---- epilogue (fully unrolled; g compile-time)
    float2* lamt = lamqs;                    // [16k][64bv]
    float2* qsh  = lamqs + 1024;
    const int col64 = tid & 63;
    const int hb = (tid >> 6) * 2;           // 2 heads per thread-quarter
    const int bl = col64 >> 5, vY = col64 & 31;
    const int bY = b0 + bl;
    float2* op2 = (float2*)out;
#pragma unroll
    for (int g = 0; g < 4; ++g) {
        __syncthreads();
        {
            int bvl = w * 16 + col;
#pragma unroll
            for (int r = 0; r < 4; ++r) {
                int k = quad * 4 + r;
                lamt[k * 64 + bvl] = make_float2(accr[g][r] + lcv[r].x,
                                                 acci[g][r] + lcv[r].y);
            }
        }
        __syncthreads();
        float yr[2], yi[2];
        yr[0] = yr[1] = yi[0] = yi[1] = 0.f;
#pragma unroll
        for (int k = 0; k < 16; ++k) {
            float2 l = lamt[k * 64 + col64];
#pragma unroll
            for (int h = 0; h < 2; ++h) {
                float2 q = qsh[(bl * 128 + (hb + h) * 16 + k) * 4 + g];
                yr[h] += q.x * l.x - q.y * l.y;
                yi[h] += q.x * l.y + q.y * l.x;
            }
        }
        int n = n0 + g;
        if (cplx) {
#pragma unroll
            for (int h = 0; h < 2; ++h)
                op2[((size_t)(bY * 256 + (hb + h) * 32 + vY)) * MM + n] = make_float2(yr[h], yi[h]);
        } else {
#pragma unroll
            for (int h = 0; h < 2; ++h)
                out[((size_t)(bY * 256 + (hb + h) * 32 + vY)) * MM + n] = yr[h];
        }
    }
}

// ---------------------------------------------------------------------------
extern "C" void kernel_launch(void* const* d_in, const int* in_sizes, int n_in,
                              void* d_out, int out_size, void* d_ws, size_t ws_size,
                              hipStream_t stream)
{
    const float* x_re  = (const float*)d_in[0];
    const float* x_im  = (const float*)d_in[1];
    const float* wq_re = (const float*)d_in[2];
    const float* wq_im = (const float*)d_in[3];
    const float* wk_re = (const float*)d_in[4];
    const float* wk_im = (const float*)d_in[5];
    const float* wv_re = (const float*)d_in[6];
    const float* wv_im = (const float*)d_in[7];
    const float* qs_re = (const float*)d_in[8];
    const float* qs_im = (const float*)d_in[9];
    const float* qb_re = (const float*)d_in[10];
    const float* qb_im = (const float*)d_in[11];
    const float* vs_re = (const float*)d_in[12];
    const float* vs_im = (const float*)d_in[13];
    const float* vb_re = (const float*)d_in[14];
    const float* vb_im = (const float*)d_in[15];
    const float* emb_re = (const float*)d_in[16];
    const float* emb_im = (const float*)d_in[17];

    float* ws = (float*)d_ws;
    const size_t O_OFF  = 0;                                     // 5,767,168
    const size_t ST_OFF = O_OFF + (size_t)BB * NCH * MM * 2;     // 640
    const size_t LC_OFF = ST_OFF + 640;                          // 16,384
    const size_t WP_OFF = LC_OFF + 16384;                        // 98,304 (Wpk)
    const size_t VR_OFF = WP_OFF + 98304;                        // 262,144
    const size_t VI_OFF = VR_OFF + 262144;                       // 262,144
    const size_t ED_OFF = VI_OFF + 262144;                       // 387,072 (embD)
    const size_t PT_OFF = ED_OFF + 387072;                       // partials

    float2*   O     = (float2*)(ws + O_OFF);
    float4*   stats = (float4*)(ws + ST_OFF);
    float2*   lamc  = (float2*)(ws + LC_OFF);
    unsigned* Wpk   = (unsigned*)(ws + WP_OFF);
    unsigned* VbfR  = (unsigned*)(ws + VR_OFF);
    unsigned* VbfI  = (unsigned*)(ws + VI_OFF);
    unsigned* embD  = (unsigned*)(ws + ED_OFF);
    double*   part  = (double*)(ws + PT_OFF);
    float*    outp  = (float*)d_out;

    int cplx = (out_size >= 2 * BB * 256 * MM) ? 1 : 0;

    k_wprep<<<dim3(96), 256, 0, stream>>>(wq_re, wq_im, wk_re, wk_im,
                                          wv_re, wv_im, Wpk);
    k_eprepD<<<dim3(1512), 256, 0, stream>>>(emb_re, emb_im, embD);
    k_proj<<<dim3(32, BB), 256, 0, stream>>>(x_re, x_im, Wpk, O);
    k_bnstats_part<<<dim3(160, 4), 256, 0, stream>>>(O, part);
    k_bnstats_fin<<<dim3(3), 64, 0, stream>>>(part, qs_re, qs_im, qb_re, qb_im,
                                              vs_re, vs_im, vb_re, vb_im, stats);
    k_bnapply<<<dim3(160, BB), 256, 0, stream>>>(stats, O, VbfR, VbfI);
    k_softlam<<<dim3(KD, BB), 256, 0, stream>>>(O, lamc);
    k_main<<<dim3(256, 8), 256, 0, stream>>>(O, embD, VbfR, VbfI, lamc, outp, cplx);
}